// Round 8
// baseline (234.864 us; speedup 1.0000x reference)
//
#include <hip/hip_runtime.h>
#include <type_traits>

// B=2, T=2048, D_MODEL=1024, H=16, Dh=64.  out = MHA_ALiBi(x) @ Wo^T
// cvt | fused QKV GEMM (V via LDS-transpose epilogue) | split-KV flash attn
// (S^T layout, P->B-operand via quad shuffles, mask path branch-split,
// l via ones-row MFMA, native __bf16 packed cvt) | combine | O proj.

#define DEV __device__ __forceinline__

typedef __attribute__((ext_vector_type(8))) short short8;     // 8 bf16
typedef __attribute__((ext_vector_type(4))) float f32x4;      // MFMA C/D
typedef __attribute__((ext_vector_type(4))) unsigned short ushort4v;
typedef __attribute__((ext_vector_type(4))) unsigned int uint4v;

DEV unsigned short f2bf(float f) {                            // RNE fp32->bf16
  unsigned u = __builtin_bit_cast(unsigned, f);
  u += 0x7fffu + ((u >> 16) & 1u);
  return (unsigned short)(u >> 16);
}
DEV float bf2f(unsigned short u) {
  unsigned x = ((unsigned)u) << 16;
  return __builtin_bit_cast(float, x);
}
DEV unsigned packbf(float lo, float hi) {  // native cvt, fusable to pk form
  __bf16 a = (__bf16)lo, b = (__bf16)hi;
  unsigned short ua, ub;
  __builtin_memcpy(&ua, &a, 2);
  __builtin_memcpy(&ub, &b, 2);
  return (unsigned)ua | ((unsigned)ub << 16);
}

DEV void gl2lds16(const void* g, void* l) {                   // 16B direct-to-LDS
  __builtin_amdgcn_global_load_lds(
      (const __attribute__((address_space(1))) void*)g,
      (__attribute__((address_space(3))) void*)l, 16, 0, 0);
}

// ---------------- fused fp32 -> bf16 convert (x + 4 weights) ---------------
__global__ __launch_bounds__(256) void cvt_all(
    const float* __restrict__ x, const float* __restrict__ wq,
    const float* __restrict__ wk, const float* __restrict__ wv,
    const float* __restrict__ wo, unsigned short* __restrict__ xb,
    unsigned short* __restrict__ wqb, unsigned short* __restrict__ wkb,
    unsigned short* __restrict__ wvb, unsigned short* __restrict__ wob) {
  int b = blockIdx.x;
  const float* s;
  unsigned short* d;
  int off;
  if (b < 4096)      { s = x;  d = xb;  off = b; }
  else if (b < 5120) { s = wq; d = wqb; off = b - 4096; }
  else if (b < 6144) { s = wk; d = wkb; off = b - 5120; }
  else if (b < 7168) { s = wv; d = wvb; off = b - 6144; }
  else               { s = wo; d = wob; off = b - 7168; }
  int i = (off * 256 + threadIdx.x) * 4;
  float4 v = *(const float4*)(s + i);
  ushort4v o = {f2bf(v.x), f2bf(v.y), f2bf(v.z), f2bf(v.w)};
  *(ushort4v*)(d + i) = o;
}

// ---------------- fused QKV GEMM: C[m,n] = sum_k A[m,k]*W[n,k] -------------
// grid (24, 32): wsel = x>>3. 128x128 tile, BK=32, m97 structure.
// (256,2): forcing 3 waves/EU caps VGPR at ~170 -> spills (R6 regression).
__global__ __launch_bounds__(256, 2) void gemm_qkv(
    const unsigned short* __restrict__ A, const unsigned short* __restrict__ Wq,
    const unsigned short* __restrict__ Wk, const unsigned short* __restrict__ Wv,
    unsigned short* __restrict__ Qo, unsigned short* __restrict__ Ko,
    unsigned short* __restrict__ Vo) {
  constexpr int K = 1024;
  __shared__ alignas(16) unsigned short Sm[18432];  // staging 8K | transpose 18.4K
  unsigned short* Al = Sm;
  unsigned short* Bl = Sm + 4096;
  const int t = threadIdx.x;
  const int l = t & 63, l15 = l & 15, l4 = l >> 4;
  const int wm = ((t >> 6) & 1) * 64, wn = (t >> 7) * 64;
  const int wsel = blockIdx.x >> 3;
  const int n0 = (blockIdx.x & 7) * 128;
  const int m0 = blockIdx.y * 128;
  const unsigned short* Bm = (wsel == 0) ? Wq : ((wsel == 1) ? Wk : Wv);

  f32x4 zero4 = {0.f, 0.f, 0.f, 0.f};
  f32x4 acc[4][4];
#pragma unroll
  for (int i = 0; i < 4; i++)
#pragma unroll
    for (int j = 0; j < 4; j++) acc[i][j] = zero4;

  const int row0 = t >> 2, seg = (t & 3) * 8;
  const unsigned short* Ag0 = A + (m0 + row0) * K + seg;
  const unsigned short* Ag1 = A + (m0 + row0 + 64) * K + seg;
  const unsigned short* Bg0 = Bm + (n0 + row0) * K + seg;
  const unsigned short* Bg1 = Bm + (n0 + row0 + 64) * K + seg;

  for (int k0 = 0; k0 < K; k0 += 32) {
    gl2lds16(Ag0 + k0, &Al[t * 8]);
    gl2lds16(Ag1 + k0, &Al[2048 + t * 8]);
    gl2lds16(Bg0 + k0, &Bl[t * 8]);
    gl2lds16(Bg1 + k0, &Bl[2048 + t * 8]);
    __syncthreads();
    short8 af[4], bf8[4];
#pragma unroll
    for (int mi = 0; mi < 4; mi++)
      af[mi] = *(const short8*)&Al[(wm + mi * 16 + l15) * 32 + l4 * 8];
#pragma unroll
    for (int ni = 0; ni < 4; ni++)
      bf8[ni] = *(const short8*)&Bl[(wn + ni * 16 + l15) * 32 + l4 * 8];
#pragma unroll
    for (int mi = 0; mi < 4; mi++)
#pragma unroll
      for (int ni = 0; ni < 4; ni++)
        acc[mi][ni] = __builtin_amdgcn_mfma_f32_16x16x32_bf16(
            af[mi], bf8[ni], acc[mi][ni], 0, 0, 0);
    __syncthreads();
  }

  if (wsel != 2) {
    unsigned short* D = (wsel == 0) ? Qo : Ko;
    const float scale = (wsel == 0) ? 0.18033688011112042f : 1.0f;  // log2e/8
#pragma unroll
    for (int mi = 0; mi < 4; mi++)
#pragma unroll
      for (int r = 0; r < 4; r++) {
        int m = m0 + wm + mi * 16 + l4 * 4 + r;
        int b = m >> 11, tt = m & 2047;
#pragma unroll
        for (int ni = 0; ni < 4; ni++) {
          int n = n0 + wn + ni * 16 + l15;
          int z = b * 16 + (n >> 6), d = n & 63;
          D[(z * 2048 + tt) * 64 + d] = f2bf(acc[mi][ni][r] * scale);
        }
      }
  } else {
    // V: acc -> per-wave LDS [d 64][t 64] stride 72, then coalesced 16B stores.
    unsigned short* Tr = Sm + (t >> 6) * 4608;
#pragma unroll
    for (int mi = 0; mi < 4; mi++)
#pragma unroll
      for (int r = 0; r < 4; r++) {
        int tl = mi * 16 + l4 * 4 + r;
#pragma unroll
        for (int ni = 0; ni < 4; ni++)
          Tr[(ni * 16 + l15) * 72 + tl] = f2bf(acc[mi][ni][r]);
      }
    __syncthreads();
    const int bb = m0 >> 11, tbase = m0 & 2047;  // batch-aware dest
#pragma unroll
    for (int it2 = 0; it2 < 8; it2++) {
      int idx = it2 * 256 + t;
      int row = idx >> 4, c = idx & 15;
      int zh = row >> 6, dd = row & 63;
      int wsrc = zh * 2 + (c >> 3);
      short8 v = *(const short8*)&Sm[wsrc * 4608 + dd * 72 + (c & 7) * 8];
      int zg = bb * 16 + (n0 >> 6) + zh;
      *(short8*)&Vo[(zg * 64 + dd) * 2048 + tbase + c * 8] = v;
    }
  }
}

// ---------------- O projection: 128x64 tiles, grid (16,32) = 512 blocks ----
__global__ __launch_bounds__(256, 2) void gemm_o(
    const unsigned short* __restrict__ A, const unsigned short* __restrict__ Bm,
    float* __restrict__ C) {
  constexpr int K = 1024;
  __shared__ alignas(16) unsigned short Al[128 * 32];
  __shared__ alignas(16) unsigned short Bl[64 * 32];
  const int t = threadIdx.x;
  const int l = t & 63, l15 = l & 15, l4 = l >> 4;
  const int wm = ((t >> 6) & 1) * 64, wn = (t >> 7) * 32;
  const int m0 = blockIdx.y * 128, n0 = blockIdx.x * 64;

  f32x4 zero4 = {0.f, 0.f, 0.f, 0.f};
  f32x4 acc[4][2];
#pragma unroll
  for (int i = 0; i < 4; i++)
#pragma unroll
    for (int j = 0; j < 2; j++) acc[i][j] = zero4;

  const int row0 = t >> 2, seg = (t & 3) * 8;
  const unsigned short* Ag0 = A + (m0 + row0) * K + seg;
  const unsigned short* Ag1 = A + (m0 + row0 + 64) * K + seg;
  const unsigned short* Bg0 = Bm + (n0 + row0) * K + seg;

  for (int k0 = 0; k0 < K; k0 += 32) {
    gl2lds16(Ag0 + k0, &Al[t * 8]);
    gl2lds16(Ag1 + k0, &Al[2048 + t * 8]);
    gl2lds16(Bg0 + k0, &Bl[t * 8]);
    __syncthreads();
    short8 af[4], bf2[2];
#pragma unroll
    for (int mi = 0; mi < 4; mi++)
      af[mi] = *(const short8*)&Al[(wm + mi * 16 + l15) * 32 + l4 * 8];
#pragma unroll
    for (int ni = 0; ni < 2; ni++)
      bf2[ni] = *(const short8*)&Bl[(wn + ni * 16 + l15) * 32 + l4 * 8];
#pragma unroll
    for (int mi = 0; mi < 4; mi++)
#pragma unroll
      for (int ni = 0; ni < 2; ni++)
        acc[mi][ni] = __builtin_amdgcn_mfma_f32_16x16x32_bf16(
            af[mi], bf2[ni], acc[mi][ni], 0, 0, 0);
    __syncthreads();
  }
#pragma unroll
  for (int mi = 0; mi < 4; mi++)
#pragma unroll
    for (int r = 0; r < 4; r++) {
      int m = m0 + wm + mi * 16 + l4 * 4 + r;
      float* cp = C + m * 1024 + n0 + wn + l15;
      cp[0] = acc[mi][0][r];
      cp[16] = acc[mi][1][r];
    }
}

// ---------------- Split-KV flash attention (S^T layout) --------------------
// grid 1024: qt = 15-(g>>6); z = (g&63)>>1; s = g&1. Side s: qt+1 kv-tiles.
// S^T via swapped QK operands; P->PV-B-operand via 3 quad-shuffles/word;
// l[q] via ones-row MFMA (C rows identical -> no reduction); masked path
// branch-split so clean tiles carry no cndmask.  LDS 32 KB -> 4 blocks/CU.
__global__ __launch_bounds__(256, 4) void flash_alibi(
    const unsigned short* __restrict__ Q, const unsigned short* __restrict__ Kb,
    const unsigned short* __restrict__ Vt, unsigned short* __restrict__ O0,
    unsigned short* __restrict__ O1, float* __restrict__ L0,
    float* __restrict__ L1) {
  __shared__ alignas(16) unsigned short Kl[2 * 4096];
  __shared__ alignas(16) unsigned short Vl[2 * 4096];
  const int t = threadIdx.x, w = t >> 6, l = t & 63, l15 = l & 15, l4 = l >> 4;
  const int g = blockIdx.x;
  const int qt = 15 - (g >> 6);
  const int z = (g & 63) >> 1, s = g & 1;
  const int q0 = qt * 128, h = z & 15;
  const float slope2 = exp2f(-0.5f * (float)(h + 1)) * 1.4426950408889634f;
  const int qrow = q0 + w * 32;

  short8 aq[2][2];  // B-operand Q frags (n=q=lane&15, k=dh=quad*8+j)
#pragma unroll
  for (int mi = 0; mi < 2; mi++)
#pragma unroll
    for (int ks = 0; ks < 2; ks++)
      aq[mi][ks] = *(const short8*)&Q[(z * 2048 + qrow + mi * 16 + l15) * 64 +
                                      ks * 32 + l4 * 8];

  const int qv0 = qrow + l15, qv1 = qrow + 16 + l15;  // per-lane q columns
  const float binit0 = -(slope2 * (float)qv0 + 10.0f);
  const float binit1 = -(slope2 * (float)qv1 + 10.0f);

  uint4v onesw = {0x3F803F80u, 0x3F803F80u, 0x3F803F80u, 0x3F803F80u};
  const short8 ones8 = __builtin_bit_cast(short8, onesw);  // bf16 1.0 x8

  f32x4 zero4 = {0.f, 0.f, 0.f, 0.f};
  f32x4 ot[4][2];  // O^T: [d-16-tile][q-16-tile]
  f32x4 lacc[2] = {zero4, zero4};  // l[q] accumulator (all rows identical)
#pragma unroll
  for (int nd = 0; nd < 4; nd++)
#pragma unroll
    for (int mi = 0; mi < 2; mi++) ot[nd][mi] = zero4;

  const int row0 = t >> 2, seg8 = (t & 3) * 8;
  const int it0 = s ? (qt + 1) : 0;
  const int nt = qt + 1;

#define ISSUE_LOADS(KV0, BUF)                                                \
  {                                                                          \
    unsigned short* Kd = &Kl[(BUF) * 4096];                                  \
    unsigned short* Vd = &Vl[(BUF) * 4096];                                  \
    gl2lds16(&Kb[(z * 2048 + (KV0) + row0) * 64 + seg8], &Kd[t * 8]);        \
    gl2lds16(&Kb[(z * 2048 + (KV0) + row0) * 64 + 32 + seg8],                \
             &Kd[2048 + t * 8]);                                             \
    gl2lds16(&Vt[(z * 64 + row0) * 2048 + (KV0) + seg8], &Vd[t * 8]);        \
    gl2lds16(&Vt[(z * 64 + row0) * 2048 + (KV0) + 32 + seg8],                \
             &Vd[2048 + t * 8]);                                             \
  }

  ISSUE_LOADS(it0 * 64, 0)

  for (int ii = 0; ii < nt; ++ii) {
    __syncthreads();  // buf (ii&1) ready
    const int kv0 = (it0 + ii) * 64;
    if (ii + 1 < nt) ISSUE_LOADS(kv0 + 64, (ii + 1) & 1)
    if (kv0 > qrow + 31) continue;  // fully masked for this wave (wave-uniform)
    const unsigned short* Kc = &Kl[(ii & 1) * 4096];
    const unsigned short* Vc = &Vl[(ii & 1) * 4096];

    // S^T = (K Q^T): sc[ni=kv-tile][mi=q-tile], init = -(slope2*q+10)
    f32x4 sc[4][2];
#pragma unroll
    for (int ni = 0; ni < 4; ni++) {
      f32x4 b0 = {binit0, binit0, binit0, binit0};
      f32x4 b1 = {binit1, binit1, binit1, binit1};
      sc[ni][0] = b0;
      sc[ni][1] = b1;
    }
#pragma unroll
    for (int ks = 0; ks < 2; ks++) {
      short8 bk[4];  // A-operand K frags (m=kv=lane&15, k=dh)
#pragma unroll
      for (int ni = 0; ni < 4; ni++)
        bk[ni] = *(const short8*)&Kc[(ks * 64 + ni * 16 + l15) * 32 + l4 * 8];
#pragma unroll
      for (int ni = 0; ni < 4; ni++)
#pragma unroll
        for (int mi = 0; mi < 2; mi++)
          sc[ni][mi] = __builtin_amdgcn_mfma_f32_16x16x32_bf16(
              bk[ni], aq[mi][ks], sc[ni][mi], 0, 0, 0);
    }

    auto softpv = [&](auto mk) {
      constexpr bool MASK = decltype(mk)::value;
#pragma unroll
      for (int ks = 0; ks < 2; ks++) {
        short8 vf[4];  // A-operand V^T frags (m=d=lane&15, k=kv)
#pragma unroll
        for (int nd = 0; nd < 4; nd++)
          vf[nd] = *(const short8*)&Vc[(ks * 64 + nd * 16 + l15) * 32 + l4 * 8];

        unsigned pk[2][2][2];  // [ni-local][mi][word]
#pragma unroll
        for (int nip = 0; nip < 2; nip++) {
          int ni = 2 * ks + nip;
          int kvb = kv0 + ni * 16 + l4 * 4;
#pragma unroll
          for (int mi = 0; mi < 2; mi++) {
            int qv = mi ? qv1 : qv0;
            float p[4];
#pragma unroll
            for (int r = 0; r < 4; r++) {
              p[r] = __builtin_amdgcn_exp2f(
                  fmaf(slope2, (float)(kvb + r), sc[ni][mi][r]));
              if constexpr (MASK) {
                if (kvb + r > qv) p[r] = 0.f;
              }
            }
            pk[nip][mi][0] = packbf(p[0], p[1]);
            pk[nip][mi][1] = packbf(p[2], p[3]);
          }
        }
#pragma unroll
        for (int mi = 0; mi < 2; mi++) {
          unsigned wd[4];
#pragma unroll
          for (int sx = 0; sx < 2; sx++) {
            unsigned X = pk[0][mi][sx], Y = pk[1][mi][sx];
            unsigned M = (l4 < 2) ? X : Y;
            unsigned N = (l4 < 2) ? Y : X;
            unsigned Mx16 = __shfl_xor((int)M, 16);
            unsigned Nx32 = __shfl_xor((int)N, 32);
            unsigned Nx48 = __shfl_xor((int)N, 48);
            wd[sx] = (l4 & 2) ? ((l4 & 1) ? Mx16 : Nx32)
                              : ((l4 & 1) ? Nx48 : M);
            wd[2 + sx] = (l4 & 2) ? ((l4 & 1) ? M : Nx48)
                                  : ((l4 & 1) ? Nx32 : Mx16);
          }
          uint4v uw = {wd[0], wd[1], wd[2], wd[3]};
          short8 pf = __builtin_bit_cast(short8, uw);
          lacc[mi] = __builtin_amdgcn_mfma_f32_16x16x32_bf16(
              ones8, pf, lacc[mi], 0, 0, 0);
#pragma unroll
          for (int nd = 0; nd < 4; nd++)
            ot[nd][mi] = __builtin_amdgcn_mfma_f32_16x16x32_bf16(
                vf[nd], pf, ot[nd][mi], 0, 0, 0);
        }
      }
    };
    if (kv0 + 63 > qrow)
      softpv(std::true_type{});
    else
      softpv(std::false_type{});
  }
#undef ISSUE_LOADS

  // epilogue: partial O (no normalization) + partial l (q = lane&15 column)
  unsigned short* Op = s ? O1 : O0;
  float* Lp = s ? L1 : L0;
#pragma unroll
  for (int mi = 0; mi < 2; mi++) {
    int qg = qrow + mi * 16 + l15;
    if (l4 == 0) Lp[z * 2048 + qg] = lacc[mi][0];
    unsigned short* op = &Op[(z * 2048 + qg) * 64 + l4 * 4];
#pragma unroll
    for (int nd = 0; nd < 4; nd++)
#pragma unroll
      for (int r = 0; r < 4; r++) op[nd * 16 + r] = f2bf(ot[nd][mi][r]);
  }
}

// ---------------- combine: O=(O0+O1)/(l0+l1), (z,t,d) -> (b,t,h*64+d) ------
__global__ __launch_bounds__(256) void combine(
    const unsigned short* __restrict__ O0, const unsigned short* __restrict__ O1,
    const float* __restrict__ L0, const float* __restrict__ L1,
    unsigned short* __restrict__ Ob) {
  int idx = (blockIdx.x * 256 + threadIdx.x) * 8;  // flat (z,t,d)
  int z = idx >> 17, rem = idx & 131071;
  int tt = rem >> 6, d = rem & 63;
  short8 a = *(const short8*)(O0 + idx);
  short8 b = *(const short8*)(O1 + idx);
  float inv = 1.0f / (L0[z * 2048 + tt] + L1[z * 2048 + tt]);
  short8 o;
#pragma unroll
  for (int j = 0; j < 8; j++) {
    float v = (bf2f((unsigned short)a[j]) + bf2f((unsigned short)b[j])) * inv;
    o[j] = (short)f2bf(v);
  }
  int bq = z >> 4, h = z & 15;
  *(short8*)(Ob + (bq * 2048 + tt) * 1024 + h * 64 + d) = o;
}

// ---------------------------------------------------------------------------
extern "C" void kernel_launch(void* const* d_in, const int* in_sizes, int n_in,
                              void* d_out, int out_size, void* d_ws,
                              size_t ws_size, hipStream_t stream) {
  const float* x = (const float*)d_in[0];
  const float* Wq = (const float*)d_in[1];
  const float* Wk = (const float*)d_in[2];
  const float* Wv = (const float*)d_in[3];
  const float* Wo = (const float*)d_in[4];

  char* p = (char*)d_ws;
  unsigned short* xb = (unsigned short*)p;  p += 4096 * 1024 * 2;  // O0 after qkv
  unsigned short* wqb = (unsigned short*)p; p += 1024 * 1024 * 2;
  unsigned short* wkb = (unsigned short*)p; p += 1024 * 1024 * 2;
  unsigned short* wvb = (unsigned short*)p; p += 1024 * 1024 * 2;
  unsigned short* wob = (unsigned short*)p; p += 1024 * 1024 * 2;
  unsigned short* Qb = (unsigned short*)p;  p += 32 * 2048 * 64 * 2;  // Ob after flash
  unsigned short* Kbf = (unsigned short*)p; p += 32 * 2048 * 64 * 2;
  unsigned short* Vtb = (unsigned short*)p; p += 32 * 2048 * 64 * 2;
  unsigned short* O1 = (unsigned short*)p;  p += 32 * 2048 * 64 * 2;
  float* L0 = (float*)p;                    p += 32 * 2048 * 4;
  float* L1 = (float*)p;                    p += 32 * 2048 * 4;
  unsigned short* O0 = xb;  // xb dead after gemm_qkv
  unsigned short* Ob = Qb;  // Qb dead after flash

  cvt_all<<<8192, 256, 0, stream>>>(x, Wq, Wk, Wv, Wo, xb, wqb, wkb, wvb, wob);
  gemm_qkv<<<dim3(24, 32), 256, 0, stream>>>(xb, wqb, wkb, wvb, Qb, Kbf, Vtb);
  flash_alibi<<<1024, 256, 0, stream>>>(Qb, Kbf, Vtb, O0, O1, L0, L1);
  combine<<<2048, 256, 0, stream>>>(O0, O1, L0, L1, Ob);
  gemm_o<<<dim3(16, 32), 256, 0, stream>>>(Ob, wob, (float*)d_out);
}

// Round 9
// 179.733 us; speedup vs baseline: 1.3067x; 1.3067x over previous
//
#include <hip/hip_runtime.h>

// B=2, T=2048, D_MODEL=1024, H=16, Dh=64.  out = MHA_ALiBi(x) @ Wo^T
// cvt | fused QKV GEMM (V via LDS-transpose epilogue) | split-KV flash attn
// (static-margin exp2 softmax -> additive partials, P LDS round-trip) |
// combine | O proj.   == R5 verified structure (178 us) + qkv x-swizzle ==

#define DEV __device__ __forceinline__

typedef __attribute__((ext_vector_type(8))) short short8;     // 8 bf16
typedef __attribute__((ext_vector_type(4))) float f32x4;      // MFMA C/D
typedef __attribute__((ext_vector_type(4))) unsigned short ushort4v;

DEV unsigned short f2bf(float f) {                            // RNE fp32->bf16
  unsigned u = __builtin_bit_cast(unsigned, f);
  u += 0x7fffu + ((u >> 16) & 1u);
  return (unsigned short)(u >> 16);
}
DEV float bf2f(unsigned short u) {
  unsigned x = ((unsigned)u) << 16;
  return __builtin_bit_cast(float, x);
}

DEV void gl2lds16(const void* g, void* l) {                   // 16B direct-to-LDS
  __builtin_amdgcn_global_load_lds(
      (const __attribute__((address_space(1))) void*)g,
      (__attribute__((address_space(3))) void*)l, 16, 0, 0);
}

// ---------------- fused fp32 -> bf16 convert (x + 4 weights) ---------------
__global__ __launch_bounds__(256) void cvt_all(
    const float* __restrict__ x, const float* __restrict__ wq,
    const float* __restrict__ wk, const float* __restrict__ wv,
    const float* __restrict__ wo, unsigned short* __restrict__ xb,
    unsigned short* __restrict__ wqb, unsigned short* __restrict__ wkb,
    unsigned short* __restrict__ wvb, unsigned short* __restrict__ wob) {
  int b = blockIdx.x;
  const float* s;
  unsigned short* d;
  int off;
  if (b < 4096)      { s = x;  d = xb;  off = b; }
  else if (b < 5120) { s = wq; d = wqb; off = b - 4096; }
  else if (b < 6144) { s = wk; d = wkb; off = b - 5120; }
  else if (b < 7168) { s = wv; d = wvb; off = b - 6144; }
  else               { s = wo; d = wob; off = b - 7168; }
  int i = (off * 256 + threadIdx.x) * 4;
  float4 v = *(const float4*)(s + i);
  ushort4v o = {f2bf(v.x), f2bf(v.y), f2bf(v.z), f2bf(v.w)};
  *(ushort4v*)(d + i) = o;
}

// ---------------- fused QKV GEMM: C[m,n] = sum_k A[m,k]*W[n,k] -------------
// grid (24, 32): wsel = x%3 (fastest -> interleaved weights, shared A panel
// stays hot in L2). 128x128 tile, BK=32, m97 structure, (256,2) (no spills).
// wsel 0: Q (scale log2e/8, (z,t,d)) | 1: K ((z,t,d)) | 2: V (z,d,t) via
// LDS-transpose epilogue with coalesced 16B stores.
__global__ __launch_bounds__(256, 2) void gemm_qkv(
    const unsigned short* __restrict__ A, const unsigned short* __restrict__ Wq,
    const unsigned short* __restrict__ Wk, const unsigned short* __restrict__ Wv,
    unsigned short* __restrict__ Qo, unsigned short* __restrict__ Ko,
    unsigned short* __restrict__ Vo) {
  constexpr int K = 1024;
  __shared__ alignas(16) unsigned short Sm[18432];  // staging 8K | transpose 18.4K
  unsigned short* Al = Sm;
  unsigned short* Bl = Sm + 4096;
  const int t = threadIdx.x;
  const int l = t & 63, l15 = l & 15, l4 = l >> 4;
  const int wm = ((t >> 6) & 1) * 64, wn = (t >> 7) * 64;
  const int wsel = blockIdx.x % 3;
  const int n0 = (blockIdx.x / 3) * 128;
  const int m0 = blockIdx.y * 128;
  const unsigned short* Bm = (wsel == 0) ? Wq : ((wsel == 1) ? Wk : Wv);

  f32x4 zero4 = {0.f, 0.f, 0.f, 0.f};
  f32x4 acc[4][4];
#pragma unroll
  for (int i = 0; i < 4; i++)
#pragma unroll
    for (int j = 0; j < 4; j++) acc[i][j] = zero4;

  const int row0 = t >> 2, seg = (t & 3) * 8;
  const unsigned short* Ag0 = A + (m0 + row0) * K + seg;
  const unsigned short* Ag1 = A + (m0 + row0 + 64) * K + seg;
  const unsigned short* Bg0 = Bm + (n0 + row0) * K + seg;
  const unsigned short* Bg1 = Bm + (n0 + row0 + 64) * K + seg;

  for (int k0 = 0; k0 < K; k0 += 32) {
    gl2lds16(Ag0 + k0, &Al[t * 8]);
    gl2lds16(Ag1 + k0, &Al[2048 + t * 8]);
    gl2lds16(Bg0 + k0, &Bl[t * 8]);
    gl2lds16(Bg1 + k0, &Bl[2048 + t * 8]);
    __syncthreads();
    short8 af[4], bf8[4];
#pragma unroll
    for (int mi = 0; mi < 4; mi++)
      af[mi] = *(const short8*)&Al[(wm + mi * 16 + l15) * 32 + l4 * 8];
#pragma unroll
    for (int ni = 0; ni < 4; ni++)
      bf8[ni] = *(const short8*)&Bl[(wn + ni * 16 + l15) * 32 + l4 * 8];
#pragma unroll
    for (int mi = 0; mi < 4; mi++)
#pragma unroll
      for (int ni = 0; ni < 4; ni++)
        acc[mi][ni] = __builtin_amdgcn_mfma_f32_16x16x32_bf16(
            af[mi], bf8[ni], acc[mi][ni], 0, 0, 0);
    __syncthreads();
  }

  if (wsel != 2) {
    unsigned short* D = (wsel == 0) ? Qo : Ko;
    const float scale = (wsel == 0) ? 0.18033688011112042f : 1.0f;  // log2e/8
#pragma unroll
    for (int mi = 0; mi < 4; mi++)
#pragma unroll
      for (int r = 0; r < 4; r++) {
        int m = m0 + wm + mi * 16 + l4 * 4 + r;
        int b = m >> 11, tt = m & 2047;
#pragma unroll
        for (int ni = 0; ni < 4; ni++) {
          int n = n0 + wn + ni * 16 + l15;
          int z = b * 16 + (n >> 6), d = n & 63;
          D[(z * 2048 + tt) * 64 + d] = f2bf(acc[mi][ni][r] * scale);
        }
      }
  } else {
    // V: acc -> per-wave LDS [d 64][t 64] stride 72, then coalesced 16B stores.
    unsigned short* Tr = Sm + (t >> 6) * 4608;
#pragma unroll
    for (int mi = 0; mi < 4; mi++)
#pragma unroll
      for (int r = 0; r < 4; r++) {
        int tl = mi * 16 + l4 * 4 + r;
#pragma unroll
        for (int ni = 0; ni < 4; ni++)
          Tr[(ni * 16 + l15) * 72 + tl] = f2bf(acc[mi][ni][r]);
      }
    __syncthreads();
    const int bb = m0 >> 11, tbase = m0 & 2047;  // batch-aware dest
#pragma unroll
    for (int it2 = 0; it2 < 8; it2++) {
      int idx = it2 * 256 + t;
      int row = idx >> 4, c = idx & 15;
      int zh = row >> 6, dd = row & 63;
      int wsrc = zh * 2 + (c >> 3);
      short8 v = *(const short8*)&Sm[wsrc * 4608 + dd * 72 + (c & 7) * 8];
      int zg = bb * 16 + (n0 >> 6) + zh;
      *(short8*)&Vo[(zg * 64 + dd) * 2048 + tbase + c * 8] = v;
    }
  }
}

// ---------------- O projection: 128x64 tiles, grid (16,32) = 512 blocks ----
__global__ __launch_bounds__(256, 2) void gemm_o(
    const unsigned short* __restrict__ A, const unsigned short* __restrict__ Bm,
    float* __restrict__ C) {
  constexpr int K = 1024;
  __shared__ alignas(16) unsigned short Al[128 * 32];
  __shared__ alignas(16) unsigned short Bl[64 * 32];
  const int t = threadIdx.x;
  const int l = t & 63, l15 = l & 15, l4 = l >> 4;
  const int wm = ((t >> 6) & 1) * 64, wn = (t >> 7) * 32;
  const int m0 = blockIdx.y * 128, n0 = blockIdx.x * 64;

  f32x4 zero4 = {0.f, 0.f, 0.f, 0.f};
  f32x4 acc[4][2];
#pragma unroll
  for (int i = 0; i < 4; i++)
#pragma unroll
    for (int j = 0; j < 2; j++) acc[i][j] = zero4;

  const int row0 = t >> 2, seg = (t & 3) * 8;
  const unsigned short* Ag0 = A + (m0 + row0) * K + seg;
  const unsigned short* Ag1 = A + (m0 + row0 + 64) * K + seg;
  const unsigned short* Bg0 = Bm + (n0 + row0) * K + seg;

  for (int k0 = 0; k0 < K; k0 += 32) {
    gl2lds16(Ag0 + k0, &Al[t * 8]);
    gl2lds16(Ag1 + k0, &Al[2048 + t * 8]);
    gl2lds16(Bg0 + k0, &Bl[t * 8]);
    __syncthreads();
    short8 af[4], bf2[2];
#pragma unroll
    for (int mi = 0; mi < 4; mi++)
      af[mi] = *(const short8*)&Al[(wm + mi * 16 + l15) * 32 + l4 * 8];
#pragma unroll
    for (int ni = 0; ni < 2; ni++)
      bf2[ni] = *(const short8*)&Bl[(wn + ni * 16 + l15) * 32 + l4 * 8];
#pragma unroll
    for (int mi = 0; mi < 4; mi++)
#pragma unroll
      for (int ni = 0; ni < 2; ni++)
        acc[mi][ni] = __builtin_amdgcn_mfma_f32_16x16x32_bf16(
            af[mi], bf2[ni], acc[mi][ni], 0, 0, 0);
    __syncthreads();
  }
#pragma unroll
  for (int mi = 0; mi < 4; mi++)
#pragma unroll
    for (int r = 0; r < 4; r++) {
      int m = m0 + wm + mi * 16 + l4 * 4 + r;
      float* cp = C + m * 1024 + n0 + wn + l15;
      cp[0] = acc[mi][0][r];
      cp[16] = acc[mi][1][r];
    }
}

// ---------------- Split-KV flash attention ---------------------------------
// grid 1024: qt = 15-(g>>6) (heavy first); z = (g&63)>>1; s = g&1.
// Side s covers kv tiles [s?qt+1:0 .. s?2qt+1:qt] — exactly qt+1 tiles each.
// Static-margin softmax (no running max) => partials combine additively.
// Masking/skip are SIDE-AGNOSTIC: qt=0 side 0 touches the diagonal.
__global__ __launch_bounds__(256, 3) void flash_alibi(
    const unsigned short* __restrict__ Q, const unsigned short* __restrict__ Kb,
    const unsigned short* __restrict__ Vt, unsigned short* __restrict__ O0,
    unsigned short* __restrict__ O1, float* __restrict__ L0,
    float* __restrict__ L1) {
  __shared__ alignas(16) unsigned short Kl[2 * 4096];
  __shared__ alignas(16) unsigned short Vl[2 * 4096];
  __shared__ alignas(16) unsigned short Pl[4 * 2304];  // 4 waves x 32 x 72
  const int t = threadIdx.x, w = t >> 6, l = t & 63, l15 = l & 15, l4 = l >> 4;
  const int g = blockIdx.x;
  const int qt = 15 - (g >> 6);
  const int z = (g & 63) >> 1, s = g & 1;
  const int q0 = qt * 128, h = z & 15;
  const float slope2 = exp2f(-0.5f * (float)(h + 1)) * 1.4426950408889634f;
  const int qrow = q0 + w * 32;

  short8 aq[2][2];
#pragma unroll
  for (int mi = 0; mi < 2; mi++)
#pragma unroll
    for (int ks = 0; ks < 2; ks++)
      aq[mi][ks] = *(const short8*)&Q[(z * 2048 + qrow + mi * 16 + l15) * 64 +
                                      ks * 32 + l4 * 8];

  f32x4 binit[2];
#pragma unroll
  for (int mi = 0; mi < 2; mi++)
#pragma unroll
    for (int r = 0; r < 4; r++)
      binit[mi][r] = -(slope2 * (float)(qrow + mi * 16 + l4 * 4 + r) + 10.0f);

  f32x4 zero4 = {0.f, 0.f, 0.f, 0.f};
  f32x4 o[2][4];
  float lsum[2][4];
#pragma unroll
  for (int mi = 0; mi < 2; mi++)
#pragma unroll
    for (int j = 0; j < 4; j++) {
      o[mi][j] = zero4;
      lsum[mi][j] = 0.f;
    }

  const int row0 = t >> 2, seg8 = (t & 3) * 8;
  const int it0 = s ? (qt + 1) : 0;
  const int nt = qt + 1;

#define ISSUE_LOADS(KV0, BUF)                                                \
  {                                                                          \
    unsigned short* Kd = &Kl[(BUF) * 4096];                                  \
    unsigned short* Vd = &Vl[(BUF) * 4096];                                  \
    gl2lds16(&Kb[(z * 2048 + (KV0) + row0) * 64 + seg8], &Kd[t * 8]);        \
    gl2lds16(&Kb[(z * 2048 + (KV0) + row0) * 64 + 32 + seg8],                \
             &Kd[2048 + t * 8]);                                             \
    gl2lds16(&Vt[(z * 64 + row0) * 2048 + (KV0) + seg8], &Vd[t * 8]);        \
    gl2lds16(&Vt[(z * 64 + row0) * 2048 + (KV0) + 32 + seg8],                \
             &Vd[2048 + t * 8]);                                             \
  }

  ISSUE_LOADS(it0 * 64, 0)

  for (int ii = 0; ii < nt; ++ii) {
    __syncthreads();  // buf (ii&1) ready
    const int kv0 = (it0 + ii) * 64;
    if (ii + 1 < nt) ISSUE_LOADS(kv0 + 64, (ii + 1) & 1)
    if (kv0 > qrow + 31) continue;  // fully masked for this wave
    const unsigned short* Kc = &Kl[(ii & 1) * 4096];
    const unsigned short* Vc = &Vl[(ii & 1) * 4096];

    f32x4 sc[2][4];
#pragma unroll
    for (int mi = 0; mi < 2; mi++)
#pragma unroll
      for (int ni = 0; ni < 4; ni++) sc[mi][ni] = binit[mi];
#pragma unroll
    for (int ks = 0; ks < 2; ks++) {
      short8 bk[4];
#pragma unroll
      for (int ni = 0; ni < 4; ni++)
        bk[ni] = *(const short8*)&Kc[(ks * 64 + ni * 16 + l15) * 32 + l4 * 8];
#pragma unroll
      for (int mi = 0; mi < 2; mi++)
#pragma unroll
        for (int ni = 0; ni < 4; ni++)
          sc[mi][ni] = __builtin_amdgcn_mfma_f32_16x16x32_bf16(
              aq[mi][ks], bk[ni], sc[mi][ni], 0, 0, 0);
    }

    const bool needMask = (kv0 + 63 > qrow);  // diagonal tile (either side)
    float jf[4];
#pragma unroll
    for (int ni = 0; ni < 4; ni++) jf[ni] = (float)(kv0 + ni * 16 + l15);

#pragma unroll
    for (int mi = 0; mi < 2; mi++)
#pragma unroll
      for (int r = 0; r < 4; r++) {
        float ps[4];
#pragma unroll
        for (int ni = 0; ni < 4; ni++)
          ps[ni] = __builtin_amdgcn_exp2f(fmaf(slope2, jf[ni], sc[mi][ni][r]));
        if (needMask) {
          int qi = qrow + mi * 16 + l4 * 4 + r;
#pragma unroll
          for (int ni = 0; ni < 4; ni++)
            if (kv0 + ni * 16 + l15 > qi) ps[ni] = 0.f;
        }
        lsum[mi][r] += (ps[0] + ps[1]) + (ps[2] + ps[3]);
        int row = mi * 16 + l4 * 4 + r;
        unsigned short* pp = &Pl[w * 2304 + row * 72 + (l15 & 7)];
#pragma unroll
        for (int ni = 0; ni < 4; ni++)
          pp[((ni * 2 + (l15 >> 3)) ^ l4) * 8] = f2bf(ps[ni]);
      }

    asm volatile("s_waitcnt lgkmcnt(0)" ::: "memory");  // wave-private P region

    const int rsw = (l15 >> 2) & 3;
#pragma unroll
    for (int ks = 0; ks < 2; ks++) {
      short8 pf[2], vf[4];
#pragma unroll
      for (int mi = 0; mi < 2; mi++)
        pf[mi] = *(const short8*)&Pl[w * 2304 + (mi * 16 + l15) * 72 +
                                     ((ks * 4 + l4) ^ rsw) * 8];
#pragma unroll
      for (int nd = 0; nd < 4; nd++)
        vf[nd] = *(const short8*)&Vc[(ks * 64 + nd * 16 + l15) * 32 + l4 * 8];
#pragma unroll
      for (int mi = 0; mi < 2; mi++)
#pragma unroll
        for (int nd = 0; nd < 4; nd++)
          o[mi][nd] = __builtin_amdgcn_mfma_f32_16x16x32_bf16(
              pf[mi], vf[nd], o[mi][nd], 0, 0, 0);
    }
  }
#undef ISSUE_LOADS

  // epilogue: write PARTIAL O (no normalization) + partial l
  unsigned short* Op = s ? O1 : O0;
  float* Lp = s ? L1 : L0;
#pragma unroll
  for (int mi = 0; mi < 2; mi++)
#pragma unroll
    for (int r = 0; r < 4; r++) {
      float lv = lsum[mi][r];
#pragma unroll
      for (int off = 1; off < 16; off <<= 1) lv += __shfl_xor(lv, off);
      int tg = qrow + mi * 16 + l4 * 4 + r;
      if (l15 == 0) Lp[z * 2048 + tg] = lv;
      unsigned short* op = &Op[(z * 2048 + tg) * 64 + l15];
#pragma unroll
      for (int nd = 0; nd < 4; nd++) op[nd * 16] = f2bf(o[mi][nd][r]);
    }
}

// ---------------- combine: O=(O0+O1)/(l0+l1), (z,t,d) -> (b,t,h*64+d) ------
__global__ __launch_bounds__(256) void combine(
    const unsigned short* __restrict__ O0, const unsigned short* __restrict__ O1,
    const float* __restrict__ L0, const float* __restrict__ L1,
    unsigned short* __restrict__ Ob) {
  int idx = (blockIdx.x * 256 + threadIdx.x) * 8;  // flat (z,t,d)
  int z = idx >> 17, rem = idx & 131071;
  int tt = rem >> 6, d = rem & 63;
  short8 a = *(const short8*)(O0 + idx);
  short8 b = *(const short8*)(O1 + idx);
  float inv = 1.0f / (L0[z * 2048 + tt] + L1[z * 2048 + tt]);
  short8 o;
#pragma unroll
  for (int j = 0; j < 8; j++) {
    float v = (bf2f((unsigned short)a[j]) + bf2f((unsigned short)b[j])) * inv;
    o[j] = (short)f2bf(v);
  }
  int bq = z >> 4, h = z & 15;
  *(short8*)(Ob + (bq * 2048 + tt) * 1024 + h * 64 + d) = o;
}

// ---------------------------------------------------------------------------
extern "C" void kernel_launch(void* const* d_in, const int* in_sizes, int n_in,
                              void* d_out, int out_size, void* d_ws,
                              size_t ws_size, hipStream_t stream) {
  const float* x = (const float*)d_in[0];
  const float* Wq = (const float*)d_in[1];
  const float* Wk = (const float*)d_in[2];
  const float* Wv = (const float*)d_in[3];
  const float* Wo = (const float*)d_in[4];

  char* p = (char*)d_ws;
  unsigned short* xb = (unsigned short*)p;  p += 4096 * 1024 * 2;  // O0 after qkv
  unsigned short* wqb = (unsigned short*)p; p += 1024 * 1024 * 2;
  unsigned short* wkb = (unsigned short*)p; p += 1024 * 1024 * 2;
  unsigned short* wvb = (unsigned short*)p; p += 1024 * 1024 * 2;
  unsigned short* wob = (unsigned short*)p; p += 1024 * 1024 * 2;
  unsigned short* Qb = (unsigned short*)p;  p += 32 * 2048 * 64 * 2;  // Ob after flash
  unsigned short* Kbf = (unsigned short*)p; p += 32 * 2048 * 64 * 2;
  unsigned short* Vtb = (unsigned short*)p; p += 32 * 2048 * 64 * 2;
  unsigned short* O1 = (unsigned short*)p;  p += 32 * 2048 * 64 * 2;
  float* L0 = (float*)p;                    p += 32 * 2048 * 4;
  float* L1 = (float*)p;                    p += 32 * 2048 * 4;
  unsigned short* O0 = xb;  // xb dead after gemm_qkv
  unsigned short* Ob = Qb;  // Qb dead after flash

  cvt_all<<<8192, 256, 0, stream>>>(x, Wq, Wk, Wv, Wo, xb, wqb, wkb, wvb, wob);
  gemm_qkv<<<dim3(24, 32), 256, 0, stream>>>(xb, wqb, wkb, wvb, Qb, Kbf, Vtb);
  flash_alibi<<<1024, 256, 0, stream>>>(Qb, Kbf, Vtb, O0, O1, L0, L1);
  combine<<<2048, 256, 0, stream>>>(O0, O1, L0, L1, Ob);
  gemm_o<<<dim3(16, 32), 256, 0, stream>>>(Ob, wob, (float*)d_out);
}

// Round 11
// 179.178 us; speedup vs baseline: 1.3108x; 1.0031x over previous
//
#include <hip/hip_runtime.h>

// B=2, T=2048, D_MODEL=1024, H=16, Dh=64.  out = MHA_ALiBi(x) @ Wo^T
// cvt | fused QKV GEMM (ALL epilogues via per-wave LDS bounce -> coalesced
// 16B stores) | split-KV flash attn (static-margin exp2 softmax) | combine |
// O proj.   == R9 verified structure + Q/K coalesced epilogue ==
// (R10 bench was an infra failure; identical resubmission.)

#define DEV __device__ __forceinline__

typedef __attribute__((ext_vector_type(8))) short short8;     // 8 bf16
typedef __attribute__((ext_vector_type(4))) float f32x4;      // MFMA C/D
typedef __attribute__((ext_vector_type(4))) unsigned short ushort4v;

DEV unsigned short f2bf(float f) {                            // RNE fp32->bf16
  unsigned u = __builtin_bit_cast(unsigned, f);
  u += 0x7fffu + ((u >> 16) & 1u);
  return (unsigned short)(u >> 16);
}
DEV float bf2f(unsigned short u) {
  unsigned x = ((unsigned)u) << 16;
  return __builtin_bit_cast(float, x);
}

DEV void gl2lds16(const void* g, void* l) {                   // 16B direct-to-LDS
  __builtin_amdgcn_global_load_lds(
      (const __attribute__((address_space(1))) void*)g,
      (__attribute__((address_space(3))) void*)l, 16, 0, 0);
}

// ---------------- fused fp32 -> bf16 convert (x + 4 weights) ---------------
__global__ __launch_bounds__(256) void cvt_all(
    const float* __restrict__ x, const float* __restrict__ wq,
    const float* __restrict__ wk, const float* __restrict__ wv,
    const float* __restrict__ wo, unsigned short* __restrict__ xb,
    unsigned short* __restrict__ wqb, unsigned short* __restrict__ wkb,
    unsigned short* __restrict__ wvb, unsigned short* __restrict__ wob) {
  int b = blockIdx.x;
  const float* s;
  unsigned short* d;
  int off;
  if (b < 4096)      { s = x;  d = xb;  off = b; }
  else if (b < 5120) { s = wq; d = wqb; off = b - 4096; }
  else if (b < 6144) { s = wk; d = wkb; off = b - 5120; }
  else if (b < 7168) { s = wv; d = wvb; off = b - 6144; }
  else               { s = wo; d = wob; off = b - 7168; }
  int i = (off * 256 + threadIdx.x) * 4;
  float4 v = *(const float4*)(s + i);
  ushort4v o = {f2bf(v.x), f2bf(v.y), f2bf(v.z), f2bf(v.w)};
  *(ushort4v*)(d + i) = o;
}

// ---------------- fused QKV GEMM: C[m,n] = sum_k A[m,k]*W[n,k] -------------
// grid (24, 32): wsel = x%3. 128x128 tile, BK=32, m97 structure, (256,2).
// wsel 0: Q (scale log2e/8, (z,t,d)) | 1: K ((z,t,d)) | 2: V (z,d,t).
// All epilogues bounce through per-wave LDS (64x72) for coalesced 16B stores.
// Each wave's 64-col slab is one h-group (wn 64-aligned), so Q/K need no
// transpose: write (t,d) rows, read back 8 rows x 8 chunks per thread.
__global__ __launch_bounds__(256, 2) void gemm_qkv(
    const unsigned short* __restrict__ A, const unsigned short* __restrict__ Wq,
    const unsigned short* __restrict__ Wk, const unsigned short* __restrict__ Wv,
    unsigned short* __restrict__ Qo, unsigned short* __restrict__ Ko,
    unsigned short* __restrict__ Vo) {
  constexpr int K = 1024;
  __shared__ alignas(16) unsigned short Sm[18432];  // staging 8K | bounce 18.4K
  unsigned short* Al = Sm;
  unsigned short* Bl = Sm + 4096;
  const int t = threadIdx.x;
  const int l = t & 63, l15 = l & 15, l4 = l >> 4;
  const int wm = ((t >> 6) & 1) * 64, wn = (t >> 7) * 64;
  const int wsel = blockIdx.x % 3;
  const int n0 = (blockIdx.x / 3) * 128;
  const int m0 = blockIdx.y * 128;
  const unsigned short* Bm = (wsel == 0) ? Wq : ((wsel == 1) ? Wk : Wv);

  f32x4 zero4 = {0.f, 0.f, 0.f, 0.f};
  f32x4 acc[4][4];
#pragma unroll
  for (int i = 0; i < 4; i++)
#pragma unroll
    for (int j = 0; j < 4; j++) acc[i][j] = zero4;

  const int row0 = t >> 2, seg = (t & 3) * 8;
  const unsigned short* Ag0 = A + (m0 + row0) * K + seg;
  const unsigned short* Ag1 = A + (m0 + row0 + 64) * K + seg;
  const unsigned short* Bg0 = Bm + (n0 + row0) * K + seg;
  const unsigned short* Bg1 = Bm + (n0 + row0 + 64) * K + seg;

  for (int k0 = 0; k0 < K; k0 += 32) {
    gl2lds16(Ag0 + k0, &Al[t * 8]);
    gl2lds16(Ag1 + k0, &Al[2048 + t * 8]);
    gl2lds16(Bg0 + k0, &Bl[t * 8]);
    gl2lds16(Bg1 + k0, &Bl[2048 + t * 8]);
    __syncthreads();
    short8 af[4], bf8[4];
#pragma unroll
    for (int mi = 0; mi < 4; mi++)
      af[mi] = *(const short8*)&Al[(wm + mi * 16 + l15) * 32 + l4 * 8];
#pragma unroll
    for (int ni = 0; ni < 4; ni++)
      bf8[ni] = *(const short8*)&Bl[(wn + ni * 16 + l15) * 32 + l4 * 8];
#pragma unroll
    for (int mi = 0; mi < 4; mi++)
#pragma unroll
      for (int ni = 0; ni < 4; ni++)
        acc[mi][ni] = __builtin_amdgcn_mfma_f32_16x16x32_bf16(
            af[mi], bf8[ni], acc[mi][ni], 0, 0, 0);
    __syncthreads();
  }
  // (last __syncthreads: all waves done with staging area -> bounce may reuse)

  const int bb = m0 >> 11, tbase = m0 & 2047;
  unsigned short* Tr = Sm + (t >> 6) * 4608;  // per-wave 64x72 region

  if (wsel != 2) {
    unsigned short* D = (wsel == 0) ? Qo : Ko;
    const float scale = (wsel == 0) ? 0.18033688011112042f : 1.0f;  // log2e/8
    // acc -> LDS rows (t_local, d): no transpose needed (wave slab = 1 h)
#pragma unroll
    for (int mi = 0; mi < 4; mi++)
#pragma unroll
      for (int r = 0; r < 4; r++) {
        int tl = mi * 16 + l4 * 4 + r;
#pragma unroll
        for (int ni = 0; ni < 4; ni++)
          Tr[tl * 72 + ni * 16 + l15] = f2bf(acc[mi][ni][r] * scale);
      }
    asm volatile("s_waitcnt lgkmcnt(0)" ::: "memory");  // wave-private region
    const int zg = bb * 16 + ((n0 + wn) >> 6);
    const int tg0 = tbase + wm;
#pragma unroll
    for (int it2 = 0; it2 < 8; it2++) {
      int row = it2 * 8 + ((l >> 3) & 7);
      short8 v = *(const short8*)&Tr[row * 72 + (l & 7) * 8];
      *(short8*)&D[(zg * 2048 + tg0 + row) * 64 + (l & 7) * 8] = v;
    }
  } else {
    // V: acc -> per-wave LDS [d 64][t 64] stride 72, coalesced stores along t.
#pragma unroll
    for (int mi = 0; mi < 4; mi++)
#pragma unroll
      for (int r = 0; r < 4; r++) {
        int tl = mi * 16 + l4 * 4 + r;
#pragma unroll
        for (int ni = 0; ni < 4; ni++)
          Tr[(ni * 16 + l15) * 72 + tl] = f2bf(acc[mi][ni][r]);
      }
    __syncthreads();  // cross-wave gather below (c>>3 picks wave region)
#pragma unroll
    for (int it2 = 0; it2 < 8; it2++) {
      int idx = it2 * 256 + t;
      int row = idx >> 4, c = idx & 15;
      int zh = row >> 6, dd = row & 63;
      int wsrc = zh * 2 + (c >> 3);
      short8 v = *(const short8*)&Sm[wsrc * 4608 + dd * 72 + (c & 7) * 8];
      int zg = bb * 16 + (n0 >> 6) + zh;
      *(short8*)&Vo[(zg * 64 + dd) * 2048 + tbase + c * 8] = v;
    }
  }
}

// ---------------- O projection: 128x64 tiles, grid (16,32) = 512 blocks ----
__global__ __launch_bounds__(256, 2) void gemm_o(
    const unsigned short* __restrict__ A, const unsigned short* __restrict__ Bm,
    float* __restrict__ C) {
  constexpr int K = 1024;
  __shared__ alignas(16) unsigned short Al[128 * 32];
  __shared__ alignas(16) unsigned short Bl[64 * 32];
  const int t = threadIdx.x;
  const int l = t & 63, l15 = l & 15, l4 = l >> 4;
  const int wm = ((t >> 6) & 1) * 64, wn = (t >> 7) * 32;
  const int m0 = blockIdx.y * 128, n0 = blockIdx.x * 64;

  f32x4 zero4 = {0.f, 0.f, 0.f, 0.f};
  f32x4 acc[4][2];
#pragma unroll
  for (int i = 0; i < 4; i++)
#pragma unroll
    for (int j = 0; j < 2; j++) acc[i][j] = zero4;

  const int row0 = t >> 2, seg = (t & 3) * 8;
  const unsigned short* Ag0 = A + (m0 + row0) * K + seg;
  const unsigned short* Ag1 = A + (m0 + row0 + 64) * K + seg;
  const unsigned short* Bg0 = Bm + (n0 + row0) * K + seg;

  for (int k0 = 0; k0 < K; k0 += 32) {
    gl2lds16(Ag0 + k0, &Al[t * 8]);
    gl2lds16(Ag1 + k0, &Al[2048 + t * 8]);
    gl2lds16(Bg0 + k0, &Bl[t * 8]);
    __syncthreads();
    short8 af[4], bf2[2];
#pragma unroll
    for (int mi = 0; mi < 4; mi++)
      af[mi] = *(const short8*)&Al[(wm + mi * 16 + l15) * 32 + l4 * 8];
#pragma unroll
    for (int ni = 0; ni < 2; ni++)
      bf2[ni] = *(const short8*)&Bl[(wn + ni * 16 + l15) * 32 + l4 * 8];
#pragma unroll
    for (int mi = 0; mi < 4; mi++)
#pragma unroll
      for (int ni = 0; ni < 2; ni++)
        acc[mi][ni] = __builtin_amdgcn_mfma_f32_16x16x32_bf16(
            af[mi], bf2[ni], acc[mi][ni], 0, 0, 0);
    __syncthreads();
  }
#pragma unroll
  for (int mi = 0; mi < 4; mi++)
#pragma unroll
    for (int r = 0; r < 4; r++) {
      int m = m0 + wm + mi * 16 + l4 * 4 + r;
      float* cp = C + m * 1024 + n0 + wn + l15;
      cp[0] = acc[mi][0][r];
      cp[16] = acc[mi][1][r];
    }
}

// ---------------- Split-KV flash attention ---------------------------------
// grid 1024: qt = 15-(g>>6) (heavy first); z = (g&63)>>1; s = g&1.
// Side s covers kv tiles [s?qt+1:0 .. s?2qt+1:qt] — exactly qt+1 tiles each.
// Static-margin softmax (no running max) => partials combine additively.
// Masking/skip are SIDE-AGNOSTIC: qt=0 side 0 touches the diagonal.
__global__ __launch_bounds__(256, 3) void flash_alibi(
    const unsigned short* __restrict__ Q, const unsigned short* __restrict__ Kb,
    const unsigned short* __restrict__ Vt, unsigned short* __restrict__ O0,
    unsigned short* __restrict__ O1, float* __restrict__ L0,
    float* __restrict__ L1) {
  __shared__ alignas(16) unsigned short Kl[2 * 4096];
  __shared__ alignas(16) unsigned short Vl[2 * 4096];
  __shared__ alignas(16) unsigned short Pl[4 * 2304];  // 4 waves x 32 x 72
  const int t = threadIdx.x, w = t >> 6, l = t & 63, l15 = l & 15, l4 = l >> 4;
  const int g = blockIdx.x;
  const int qt = 15 - (g >> 6);
  const int z = (g & 63) >> 1, s = g & 1;
  const int q0 = qt * 128, h = z & 15;
  const float slope2 = exp2f(-0.5f * (float)(h + 1)) * 1.4426950408889634f;
  const int qrow = q0 + w * 32;

  short8 aq[2][2];
#pragma unroll
  for (int mi = 0; mi < 2; mi++)
#pragma unroll
    for (int ks = 0; ks < 2; ks++)
      aq[mi][ks] = *(const short8*)&Q[(z * 2048 + qrow + mi * 16 + l15) * 64 +
                                      ks * 32 + l4 * 8];

  f32x4 binit[2];
#pragma unroll
  for (int mi = 0; mi < 2; mi++)
#pragma unroll
    for (int r = 0; r < 4; r++)
      binit[mi][r] = -(slope2 * (float)(qrow + mi * 16 + l4 * 4 + r) + 10.0f);

  f32x4 zero4 = {0.f, 0.f, 0.f, 0.f};
  f32x4 o[2][4];
  float lsum[2][4];
#pragma unroll
  for (int mi = 0; mi < 2; mi++)
#pragma unroll
    for (int j = 0; j < 4; j++) {
      o[mi][j] = zero4;
      lsum[mi][j] = 0.f;
    }

  const int row0 = t >> 2, seg8 = (t & 3) * 8;
  const int it0 = s ? (qt + 1) : 0;
  const int nt = qt + 1;

#define ISSUE_LOADS(KV0, BUF)                                                \
  {                                                                          \
    unsigned short* Kd = &Kl[(BUF) * 4096];                                  \
    unsigned short* Vd = &Vl[(BUF) * 4096];                                  \
    gl2lds16(&Kb[(z * 2048 + (KV0) + row0) * 64 + seg8], &Kd[t * 8]);        \
    gl2lds16(&Kb[(z * 2048 + (KV0) + row0) * 64 + 32 + seg8],                \
             &Kd[2048 + t * 8]);                                             \
    gl2lds16(&Vt[(z * 64 + row0) * 2048 + (KV0) + seg8], &Vd[t * 8]);        \
    gl2lds16(&Vt[(z * 64 + row0) * 2048 + (KV0) + 32 + seg8],                \
             &Vd[2048 + t * 8]);                                             \
  }

  ISSUE_LOADS(it0 * 64, 0)

  for (int ii = 0; ii < nt; ++ii) {
    __syncthreads();  // buf (ii&1) ready
    const int kv0 = (it0 + ii) * 64;
    if (ii + 1 < nt) ISSUE_LOADS(kv0 + 64, (ii + 1) & 1)
    if (kv0 > qrow + 31) continue;  // fully masked for this wave
    const unsigned short* Kc = &Kl[(ii & 1) * 4096];
    const unsigned short* Vc = &Vl[(ii & 1) * 4096];

    f32x4 sc[2][4];
#pragma unroll
    for (int mi = 0; mi < 2; mi++)
#pragma unroll
      for (int ni = 0; ni < 4; ni++) sc[mi][ni] = binit[mi];
#pragma unroll
    for (int ks = 0; ks < 2; ks++) {
      short8 bk[4];
#pragma unroll
      for (int ni = 0; ni < 4; ni++)
        bk[ni] = *(const short8*)&Kc[(ks * 64 + ni * 16 + l15) * 32 + l4 * 8];
#pragma unroll
      for (int mi = 0; mi < 2; mi++)
#pragma unroll
        for (int ni = 0; ni < 4; ni++)
          sc[mi][ni] = __builtin_amdgcn_mfma_f32_16x16x32_bf16(
              aq[mi][ks], bk[ni], sc[mi][ni], 0, 0, 0);
    }

    const bool needMask = (kv0 + 63 > qrow);  // diagonal tile (either side)
    float jf[4];
#pragma unroll
    for (int ni = 0; ni < 4; ni++) jf[ni] = (float)(kv0 + ni * 16 + l15);

#pragma unroll
    for (int mi = 0; mi < 2; mi++)
#pragma unroll
      for (int r = 0; r < 4; r++) {
        float ps[4];
#pragma unroll
        for (int ni = 0; ni < 4; ni++)
          ps[ni] = __builtin_amdgcn_exp2f(fmaf(slope2, jf[ni], sc[mi][ni][r]));
        if (needMask) {
          int qi = qrow + mi * 16 + l4 * 4 + r;
#pragma unroll
          for (int ni = 0; ni < 4; ni++)
            if (kv0 + ni * 16 + l15 > qi) ps[ni] = 0.f;
        }
        lsum[mi][r] += (ps[0] + ps[1]) + (ps[2] + ps[3]);
        int row = mi * 16 + l4 * 4 + r;
        unsigned short* pp = &Pl[w * 2304 + row * 72 + (l15 & 7)];
#pragma unroll
        for (int ni = 0; ni < 4; ni++)
          pp[((ni * 2 + (l15 >> 3)) ^ l4) * 8] = f2bf(ps[ni]);
      }

    asm volatile("s_waitcnt lgkmcnt(0)" ::: "memory");  // wave-private P region

    const int rsw = (l15 >> 2) & 3;
#pragma unroll
    for (int ks = 0; ks < 2; ks++) {
      short8 pf[2], vf[4];
#pragma unroll
      for (int mi = 0; mi < 2; mi++)
        pf[mi] = *(const short8*)&Pl[w * 2304 + (mi * 16 + l15) * 72 +
                                     ((ks * 4 + l4) ^ rsw) * 8];
#pragma unroll
      for (int nd = 0; nd < 4; nd++)
        vf[nd] = *(const short8*)&Vc[(ks * 64 + nd * 16 + l15) * 32 + l4 * 8];
#pragma unroll
      for (int mi = 0; mi < 2; mi++)
#pragma unroll
        for (int nd = 0; nd < 4; nd++)
          o[mi][nd] = __builtin_amdgcn_mfma_f32_16x16x32_bf16(
              pf[mi], vf[nd], o[mi][nd], 0, 0, 0);
    }
  }
#undef ISSUE_LOADS

  // epilogue: write PARTIAL O (no normalization) + partial l
  unsigned short* Op = s ? O1 : O0;
  float* Lp = s ? L1 : L0;
#pragma unroll
  for (int mi = 0; mi < 2; mi++)
#pragma unroll
    for (int r = 0; r < 4; r++) {
      float lv = lsum[mi][r];
#pragma unroll
      for (int off = 1; off < 16; off <<= 1) lv += __shfl_xor(lv, off);
      int tg = qrow + mi * 16 + l4 * 4 + r;
      if (l15 == 0) Lp[z * 2048 + tg] = lv;
      unsigned short* op = &Op[(z * 2048 + tg) * 64 + l15];
#pragma unroll
      for (int nd = 0; nd < 4; nd++) op[nd * 16] = f2bf(o[mi][nd][r]);
    }
}

// ---------------- combine: O=(O0+O1)/(l0+l1), (z,t,d) -> (b,t,h*64+d) ------
__global__ __launch_bounds__(256) void combine(
    const unsigned short* __restrict__ O0, const unsigned short* __restrict__ O1,
    const float* __restrict__ L0, const float* __restrict__ L1,
    unsigned short* __restrict__ Ob) {
  int idx = (blockIdx.x * 256 + threadIdx.x) * 8;  // flat (z,t,d)
  int z = idx >> 17, rem = idx & 131071;
  int tt = rem >> 6, d = rem & 63;
  short8 a = *(const short8*)(O0 + idx);
  short8 b = *(const short8*)(O1 + idx);
  float inv = 1.0f / (L0[z * 2048 + tt] + L1[z * 2048 + tt]);
  short8 o;
#pragma unroll
  for (int j = 0; j < 8; j++) {
    float v = (bf2f((unsigned short)a[j]) + bf2f((unsigned short)b[j])) * inv;
    o[j] = (short)f2bf(v);
  }
  int bq = z >> 4, h = z & 15;
  *(short8*)(Ob + (bq * 2048 + tt) * 1024 + h * 64 + d) = o;
}

// ---------------------------------------------------------------------------
extern "C" void kernel_launch(void* const* d_in, const int* in_sizes, int n_in,
                              void* d_out, int out_size, void* d_ws,
                              size_t ws_size, hipStream_t stream) {
  const float* x = (const float*)d_in[0];
  const float* Wq = (const float*)d_in[1];
  const float* Wk = (const float*)d_in[2];
  const float* Wv = (const float*)d_in[3];
  const float* Wo = (const float*)d_in[4];

  char* p = (char*)d_ws;
  unsigned short* xb = (unsigned short*)p;  p += 4096 * 1024 * 2;  // O0 after qkv
  unsigned short* wqb = (unsigned short*)p; p += 1024 * 1024 * 2;
  unsigned short* wkb = (unsigned short*)p; p += 1024 * 1024 * 2;
  unsigned short* wvb = (unsigned short*)p; p += 1024 * 1024 * 2;
  unsigned short* wob = (unsigned short*)p; p += 1024 * 1024 * 2;
  unsigned short* Qb = (unsigned short*)p;  p += 32 * 2048 * 64 * 2;  // Ob after flash
  unsigned short* Kbf = (unsigned short*)p; p += 32 * 2048 * 64 * 2;
  unsigned short* Vtb = (unsigned short*)p; p += 32 * 2048 * 64 * 2;
  unsigned short* O1 = (unsigned short*)p;  p += 32 * 2048 * 64 * 2;
  float* L0 = (float*)p;                    p += 32 * 2048 * 4;
  float* L1 = (float*)p;                    p += 32 * 2048 * 4;
  unsigned short* O0 = xb;  // xb dead after gemm_qkv
  unsigned short* Ob = Qb;  // Qb dead after flash

  cvt_all<<<8192, 256, 0, stream>>>(x, Wq, Wk, Wv, Wo, xb, wqb, wkb, wvb, wob);
  gemm_qkv<<<dim3(24, 32), 256, 0, stream>>>(xb, wqb, wkb, wvb, Qb, Kbf, Vtb);
  flash_alibi<<<1024, 256, 0, stream>>>(Qb, Kbf, Vtb, O0, O1, L0, L1);
  combine<<<2048, 256, 0, stream>>>(O0, O1, L0, L1, Ob);
  gemm_o<<<dim3(16, 32), 256, 0, stream>>>(Ob, wob, (float*)d_out);
}